// Round 4
// baseline (326.121 us; speedup 1.0000x reference)
//
#include <hip/hip_runtime.h>
#include <hip/hip_bf16.h>
#include <stdint.h>
#include <math.h>

// B=4, S=2048, D=1024 causal self-attention, f32 I/O.
// out = [output (4,2048,1024) | attn_weights (4,2048,2048)] flat f32.
// Pipeline: cvt(f32->bf16) -> fused QKV GEMM -> causal-tile scores GEMM
// -> in-place row softmax (+bf16 P copy) -> P.Vt GEMM.
// R11 (from R9's regression: qkv 93us, MfmaUtil 21.5%, FETCH 59.5MB):
//  - gemm_core8 v2: stages pushed to earliest WAR-legal phase (4-5 phase
//    lookahead vs R9's 2-3), uniform vmcnt(10) at phases 2/4, peeled
//    2-tile epilogue with vmcnt(8)/(4)/(0). Ledger hand-verified.
//  - qkv XCD decode z-major: per XCD one W matrix (2MB) + one X tile
//    (0.5MB) resident -> fits 4MB L2 (R9 grouped 6MB of W -> thrash).

typedef __hip_bfloat16 bf16;
typedef __attribute__((ext_vector_type(8))) short short8;
typedef __attribute__((ext_vector_type(4))) float f32x4;

#define BM 128
#define BN 128
#define BK 64

static constexpr int Bb = 4;
static constexpr int S  = 2048;
static constexpr int D  = 1024;
static constexpr size_t QK_ELEMS = (size_t)Bb * S * D;   // 8388608
static constexpr size_t SS_ELEMS = (size_t)S * S;        // 4194304 per batch
static constexpr size_t W_ELEMS  = (size_t)D * D;        // 1048576

__device__ __forceinline__ void async16(const bf16* g, bf16* l) {
  __builtin_amdgcn_global_load_lds(
      (__attribute__((address_space(1))) const void*)g,
      (__attribute__((address_space(3))) void*)l, 16, 0, 0);
}

// ===================== legacy 128x128 core (out_kernel) ====================
template<bool SWAP>
__device__ __forceinline__ void gemm_core(const bf16* __restrict__ A,
                                          const bf16* __restrict__ B,
                                          int ldA, int ldB, int ksteps,
                                          bf16* As, bf16* Bs,
                                          f32x4 acc[4][4])
{
  const int tid  = threadIdx.x;
  const int lane = tid & 63;
  const int wave = tid >> 6;
  const int wm   = (wave & 1) * 64;
  const int wn   = (wave >> 1) * 64;
  const int m16  = lane & 15;
  const int kq   = lane >> 4;
  const int sw   = m16 & 7;          // row-dependent swizzle key

  int r[4], f[4];
  #pragma unroll
  for (int i = 0; i < 4; ++i) {
    const int c = tid + i * 256;
    r[i] = c >> 3;
    f[i] = (((c & 7) ^ (r[i] & 7))) * 8;
  }

  for (int ks = 0; ks < ksteps; ++ks) {
    const int k = ks * BK;
    #pragma unroll
    for (int i = 0; i < 4; ++i)
      async16(A + (size_t)r[i] * ldA + k + f[i], As + ((size_t)tid + i * 256) * 8);
    #pragma unroll
    for (int i = 0; i < 4; ++i)
      async16(B + (size_t)r[i] * ldB + k + f[i], Bs + ((size_t)tid + i * 256) * 8);
    __syncthreads();

    #pragma unroll
    for (int j = 0; j < 2; ++j) {
      const int jc = j * 4 + kq;       // logical K-chunk for this lane
      const int sl = jc ^ sw;          // swizzled LDS slot within row
      short8 af[4], bfr[4];
      #pragma unroll
      for (int i = 0; i < 4; ++i)
        af[i] = *(const short8*)&As[((wm + i * 16 + m16) * 8 + sl) * 8];
      #pragma unroll
      for (int i = 0; i < 4; ++i)
        bfr[i] = *(const short8*)&Bs[((wn + i * 16 + m16) * 8 + sl) * 8];

      #pragma unroll
      for (int mi = 0; mi < 4; ++mi) {
        #pragma unroll
        for (int ni = 0; ni < 4; ++ni) {
          if (SWAP)
            acc[mi][ni] = __builtin_amdgcn_mfma_f32_16x16x32_bf16(
                bfr[ni], af[mi], acc[mi][ni], 0, 0, 0);
          else
            acc[mi][ni] = __builtin_amdgcn_mfma_f32_16x16x32_bf16(
                af[mi], bfr[ni], acc[mi][ni], 0, 0, 0);
        }
      }
    }
    __syncthreads();
  }
}

__device__ __forceinline__ void zero_acc(f32x4 acc[4][4]) {
  #pragma unroll
  for (int mi = 0; mi < 4; ++mi)
    #pragma unroll
    for (int ni = 0; ni < 4; ++ni)
      acc[mi][ni] = (f32x4){0.f, 0.f, 0.f, 0.f};
}

// ================== 256x256 8-wave pipelined core, v2 ======================
// LDS (bf16 elems): buffer par in {0,1} at par*32768; A at +0, B at +16384.
// K-major: chunk c (16B of K) at c*2048, row r at +r*8. K-tile = 8 chunks.
// Half-tile H(t,j): j=0 A-ks0, j=1 B-ks0, j=2 A-ks1, j=3 B-ks1 (8192 elems).
// Stage schedule (earliest WAR-legal):
//   t.p1 -> H(t+1,2)   t.p2 -> H(t+2,1)   t.p3 -> H(t+2,0)   t.p4 -> H(t+2,3)
// Waits: vmcnt(10) at p2 (guarantees ks1(t) for p3 reads) and p4
// (guarantees ks0(t+1) for next p1 reads). 4-5 phases of load cover.

#define LOAD_A8(mh, ks) {                                                   \
    const bf16* ap_ = Areg + ((ks)*4 + kq)*2048 +                           \
                      (wm*128 + (mh)*64 + m16)*8;                           \
    af[0] = *(const short8*)(ap_);                                          \
    af[1] = *(const short8*)(ap_ + 128);                                    \
    af[2] = *(const short8*)(ap_ + 256);                                    \
    af[3] = *(const short8*)(ap_ + 384); }

#define LOAD_B8(ks) {                                                       \
    const bf16* bp_ = Breg + ((ks)*4 + kq)*2048 + (wn + m16)*8;             \
    bfr[0] = *(const short8*)(bp_);                                         \
    bfr[1] = *(const short8*)(bp_ + 128);                                   \
    bfr[2] = *(const short8*)(bp_ + 256);                                   \
    bfr[3] = *(const short8*)(bp_ + 384); }

#define MFMA_QUAD8(mh)                                                      \
    __builtin_amdgcn_s_setprio(1);                                          \
    _Pragma("unroll")                                                       \
    for (int mf = 0; mf < 4; ++mf) {                                        \
      _Pragma("unroll")                                                     \
      for (int nf = 0; nf < 4; ++nf) {                                      \
        if (SWAP)                                                           \
          acc[(mh)*4 + mf][nf] = __builtin_amdgcn_mfma_f32_16x16x32_bf16(   \
              bfr[nf], af[mf], acc[(mh)*4 + mf][nf], 0, 0, 0);              \
        else                                                                \
          acc[(mh)*4 + mf][nf] = __builtin_amdgcn_mfma_f32_16x16x32_bf16(   \
              af[mf], bfr[nf], acc[(mh)*4 + mf][nf], 0, 0, 0);              \
      }                                                                     \
    }                                                                       \
    __builtin_amdgcn_s_setprio(0);

template<bool SWAP>
__device__ __forceinline__ void gemm_core8(const bf16* __restrict__ A,
                                           const bf16* __restrict__ B,
                                           int ldA, int ldB, int ktiles,
                                           bf16* lds, f32x4 acc[8][4])
{
  const int tid  = threadIdx.x;          // 0..511
  const int lane = tid & 63;
  const int wave = tid >> 6;             // 0..7
  const int wm   = (wave >> 2) & 1;      // M row-half of 256
  const int wn   = (wave & 3) * 64;      // N col block of 64
  const int m16  = lane & 15;
  const int kq   = lane >> 4;

  // stage one (matrix, K-half): 16KB, 2 x async16 per thread, lane-linear.
  auto stage_half = [&](const bf16* Mat, int ld, int par, int matid, int ks) {
    bf16* base = lds + par * 32768 + matid * 16384 + ks * 8192;
    #pragma unroll
    for (int i = 0; i < 2; ++i) {
      const int q = tid + i * 512;       // 0..1023 chunk-slot
      async16(Mat + (size_t)(q & 255) * ld + ks * 32 + (q >> 8) * 8,
              base + q * 8);
    }
  };

  // prologue: 7 stages: H(0,0..3), H(1,0), H(1,1), H(1,3). (H(1,2) comes
  // from t=0.p1.) Then vmcnt(10) drains the oldest 2 stages = ks0(0).
  stage_half(A,      ldA, 0, 0, 0);      // #1 A-ks0 t0
  stage_half(B,      ldB, 0, 1, 0);      // #2 B-ks0 t0
  stage_half(A,      ldA, 0, 0, 1);      // #3 A-ks1 t0
  stage_half(B,      ldB, 0, 1, 1);      // #4 B-ks1 t0
  stage_half(A + 64, ldA, 1, 0, 0);      // #5 A-ks0 t1
  stage_half(B + 64, ldB, 1, 1, 0);      // #6 B-ks0 t1
  stage_half(B + 64, ldB, 1, 1, 1);      // #7 B-ks1 t1
  asm volatile("s_waitcnt vmcnt(10)" ::: "memory");
  __builtin_amdgcn_s_barrier();

  // main loop: t = 0 .. ktiles-3 (all stage targets valid)
  for (int t = 0; t + 2 < ktiles; ++t) {
    const int par = t & 1, npar = par ^ 1;
    const bf16* __restrict__ Areg = lds + par * 32768;
    const bf16* __restrict__ Breg = Areg + 16384;
    const bf16* A1 = A + (size_t)(t + 1) * 64;
    const bf16* A2 = A + (size_t)(t + 2) * 64;
    const bf16* B2 = B + (size_t)(t + 2) * 64;
    short8 af[4], bfr[4];

    // p1: read ks0 (mh0 + B); stage A-ks1(t+1)
    LOAD_B8(0);
    LOAD_A8(0, 0);
    stage_half(A1, ldA, npar, 0, 1);
    __builtin_amdgcn_s_barrier();
    MFMA_QUAD8(0);
    __builtin_amdgcn_s_barrier();

    // p2: read A mh1 ks0; stage B-ks0(t+2); vmcnt(10) -> ks1(t) landed
    LOAD_A8(1, 0);
    stage_half(B2, ldB, par, 1, 0);
    asm volatile("s_waitcnt vmcnt(10)" ::: "memory");
    __builtin_amdgcn_s_barrier();
    MFMA_QUAD8(1);
    __builtin_amdgcn_s_barrier();

    // p3: read ks1 (mh0 + B); stage A-ks0(t+2)
    LOAD_B8(1);
    LOAD_A8(0, 1);
    stage_half(A2, ldA, par, 0, 0);
    __builtin_amdgcn_s_barrier();
    MFMA_QUAD8(0);
    __builtin_amdgcn_s_barrier();

    // p4: read A mh1 ks1; stage B-ks1(t+2); vmcnt(10) -> ks0(t+1) landed
    LOAD_A8(1, 1);
    stage_half(B2, ldB, par, 1, 1);
    asm volatile("s_waitcnt vmcnt(10)" ::: "memory");
    __builtin_amdgcn_s_barrier();
    MFMA_QUAD8(1);
    __builtin_amdgcn_s_barrier();
  }

  // epilogue tile e0 = ktiles-2
  {
    const int t = ktiles - 2;
    const int par = t & 1, npar = par ^ 1;
    const bf16* __restrict__ Areg = lds + par * 32768;
    const bf16* __restrict__ Breg = Areg + 16384;
    const bf16* A1 = A + (size_t)(t + 1) * 64;
    short8 af[4], bfr[4];

    // p1: read ks0; stage A-ks1(kt-1) (last stage overall)
    LOAD_B8(0);
    LOAD_A8(0, 0);
    stage_half(A1, ldA, npar, 0, 1);
    __builtin_amdgcn_s_barrier();
    MFMA_QUAD8(0);
    __builtin_amdgcn_s_barrier();

    // p2: vmcnt(8) -> ks1(e0) landed (4 stages issued after A-ks1(e0))
    LOAD_A8(1, 0);
    asm volatile("s_waitcnt vmcnt(8)" ::: "memory");
    __builtin_amdgcn_s_barrier();
    MFMA_QUAD8(1);
    __builtin_amdgcn_s_barrier();

    // p3: read ks1
    LOAD_B8(1);
    LOAD_A8(0, 1);
    __builtin_amdgcn_s_barrier();
    MFMA_QUAD8(0);
    __builtin_amdgcn_s_barrier();

    // p4: vmcnt(4) -> ks0(kt-1) landed (2 stages after A-ks0(kt-1))
    LOAD_A8(1, 1);
    asm volatile("s_waitcnt vmcnt(4)" ::: "memory");
    __builtin_amdgcn_s_barrier();
    MFMA_QUAD8(1);
    __builtin_amdgcn_s_barrier();
  }

  // epilogue tile e1 = ktiles-1
  {
    const int t = ktiles - 1;
    const int par = t & 1;
    const bf16* __restrict__ Areg = lds + par * 32768;
    const bf16* __restrict__ Breg = Areg + 16384;
    short8 af[4], bfr[4];

    // p1: read ks0 (guaranteed by e0.p4's vmcnt(4) + barrier)
    LOAD_B8(0);
    LOAD_A8(0, 0);
    __builtin_amdgcn_s_barrier();
    MFMA_QUAD8(0);
    __builtin_amdgcn_s_barrier();

    // p2: vmcnt(0) -> everything landed (covers ks1(kt-1))
    LOAD_A8(1, 0);
    asm volatile("s_waitcnt vmcnt(0)" ::: "memory");
    __builtin_amdgcn_s_barrier();
    MFMA_QUAD8(1);
    __builtin_amdgcn_s_barrier();

    // p3: read ks1
    LOAD_B8(1);
    LOAD_A8(0, 1);
    __builtin_amdgcn_s_barrier();
    MFMA_QUAD8(0);
    __builtin_amdgcn_s_barrier();

    // p4
    LOAD_A8(1, 1);
    __builtin_amdgcn_s_barrier();
    MFMA_QUAD8(1);
  }
}

__device__ __forceinline__ void zero_acc8(f32x4 acc[8][4]) {
  #pragma unroll
  for (int a = 0; a < 8; ++a)
    #pragma unroll
    for (int nf = 0; nf < 4; ++nf)
      acc[a][nf] = (f32x4){0.f, 0.f, 0.f, 0.f};
}

// ---- Stage 0: f32 -> bf16 conversion of X, Wq, Wk, Wv --------------------
__device__ __forceinline__ unsigned short f2b(float f) {
  __hip_bfloat16 h = __float2bfloat16(f);
  return *(unsigned short*)&h;
}

__global__ __launch_bounds__(256)
void cvt_kernel(const float* __restrict__ X,  const float* __restrict__ Wq,
                const float* __restrict__ Wk, const float* __restrict__ Wv,
                bf16* __restrict__ Xb, bf16* __restrict__ Wqb,
                bf16* __restrict__ Wkb, bf16* __restrict__ Wvb)
{
  const size_t g = ((size_t)blockIdx.x * 256 + threadIdx.x) * 4;
  const float* src; bf16* dst; size_t off;
  if (g < QK_ELEMS) { src = X; dst = Xb; off = g; }
  else {
    const size_t h = g - QK_ELEMS;
    const int w = (int)(h >> 20);
    off = h & (W_ELEMS - 1);
    src = (w == 0) ? Wq : (w == 1) ? Wk : Wv;
    dst = (w == 0) ? Wqb : (w == 1) ? Wkb : Wvb;
  }
  const float4 v = *(const float4*)(src + off);
  uint2 o;
  o.x = (uint32_t)f2b(v.x) | ((uint32_t)f2b(v.y) << 16);
  o.y = (uint32_t)f2b(v.z) | ((uint32_t)f2b(v.w) << 16);
  *(uint2*)((unsigned short*)dst + off) = o;
}

// ---- Stage A: fused QKV on the 256x256 core. 384 blocks, z-major XCD.
// Per XCD: one z at a time (W(z) 2MB resident) x 4 mt x 4 nt; nt fastest.
__global__ __launch_bounds__(512, 2)
void qkv_kernel(const bf16* __restrict__ X, const bf16* __restrict__ Wq,
                const bf16* __restrict__ Wk, const bf16* __restrict__ Wv,
                bf16* __restrict__ Q, bf16* __restrict__ Ko,
                bf16* __restrict__ Vt)
{
  __shared__ __align__(16) bf16 lds[65536];     // 128KB
  const int L   = blockIdx.x;                   // 0..383
  const int xcd = L & 7;
  const int G   = L >> 3;                       // 0..47
  const int z   = G >> 4;                       // 0..2 (z-major per XCD)
  const int r_  = G & 15;
  const int mt  = xcd * 4 + (r_ >> 2);          // 0..31 X row-tile
  const int nt  = r_ & 3;                       // 0..3 col-tile (fastest)
  const bf16* W = (z == 0) ? Wq : (z == 1) ? Wk : Wv;

  const int tid = threadIdx.x;
  const int lane = tid & 63, wave = tid >> 6;
  const int wm = (wave >> 2) & 1, wn = (wave & 3) * 64;
  const int col0 = lane & 15, row0 = (lane >> 4) * 4;

  f32x4 acc[8][4];
  zero_acc8(acc);
  if (z < 2) {
    gemm_core8<false>(X + (size_t)mt * 256 * D, W + (size_t)nt * 256 * D,
                      D, D, D / 64, lds, acc);
    bf16* Out = z ? Ko : Q;
    #pragma unroll
    for (int a = 0; a < 8; ++a)
      #pragma unroll
      for (int nf = 0; nf < 4; ++nf)
        #pragma unroll
        for (int r = 0; r < 4; ++r) {
          const int grow = mt * 256 + wm * 128 + a * 16 + row0 + r;
          const int gcol = nt * 256 + wn + nf * 16 + col0;
          Out[(size_t)grow * D + gcol] = __float2bfloat16(acc[a][nf][r]);
        }
  } else {
    gemm_core8<true>(X + (size_t)mt * 256 * D, W + (size_t)nt * 256 * D,
                     D, D, D / 64, lds, acc);
    const int b = mt >> 3;                      // 8 row-tiles per batch
    #pragma unroll
    for (int a = 0; a < 8; ++a)
      #pragma unroll
      for (int nf = 0; nf < 4; ++nf)
        #pragma unroll
        for (int r = 0; r < 4; ++r) {
          const int ge = nt * 256 + wn + nf * 16 + row0 + r;   // d index
          const int gs = mt * 256 + wm * 128 + a * 16 + col0;  // s global
          const int sl = gs & (S - 1);
          Vt[(size_t)b * D * S + (size_t)ge * S + sl] = __float2bfloat16(acc[a][nf][r]);
        }
  }
}

// ---- Stage B: Sc = Q K^T / 32 on the 256x256 core. 36 tiles/batch. -------
__global__ __launch_bounds__(512, 2)
void scores_kernel(const bf16* __restrict__ Q, const bf16* __restrict__ K,
                   float* __restrict__ Sc)
{
  const int t = blockIdx.x, b = blockIdx.y;
  int qt = (int)((sqrtf(8.f * (float)t + 1.f) - 1.f) * 0.5f);
  while ((qt + 1) * (qt + 2) / 2 <= t) ++qt;
  while (qt * (qt + 1) / 2 > t) --qt;
  const int kt = t - qt * (qt + 1) / 2;

  __shared__ __align__(16) bf16 lds[65536];     // 128KB

  f32x4 acc[8][4];
  zero_acc8(acc);
  gemm_core8<false>(Q + ((size_t)b * S + qt * 256) * D,
                    K + ((size_t)b * S + kt * 256) * D,
                    D, D, D / 64, lds, acc);

  const int tid = threadIdx.x;
  const int lane = tid & 63, wave = tid >> 6;
  const int wm = (wave >> 2) & 1, wn = (wave & 3) * 64;
  const int col0 = lane & 15, row0 = (lane >> 4) * 4;
  float* out = Sc + (size_t)b * SS_ELEMS;
  #pragma unroll
  for (int a = 0; a < 8; ++a)
    #pragma unroll
    for (int nf = 0; nf < 4; ++nf)
      #pragma unroll
      for (int r = 0; r < 4; ++r) {
        const int gq = qt * 256 + wm * 128 + a * 16 + row0 + r;
        const int gk = kt * 256 + wn + nf * 16 + col0;
        out[(size_t)gq * S + gk] = acc[a][nf][r] * 0.03125f;
      }
}

// ---- Stage C: causal row softmax in place (f32) + bf16 P copy ------------
__device__ __forceinline__ float wave_max(float v) {
  #pragma unroll
  for (int o = 32; o > 0; o >>= 1) v = fmaxf(v, __shfl_xor(v, o, 64));
  return v;
}
__device__ __forceinline__ float wave_sum(float v) {
  #pragma unroll
  for (int o = 32; o > 0; o >>= 1) v += __shfl_xor(v, o, 64);
  return v;
}

__global__ __launch_bounds__(256)
void softmax_kernel(float* __restrict__ Attn, bf16* __restrict__ Pb)
{
  const int row = blockIdx.x;            // 0..8191
  const int b = row >> 11, i = row & (S - 1);
  float* s = Attn + (size_t)b * SS_ELEMS + (size_t)i * S;
  bf16* p  = Pb   + (size_t)b * SS_ELEMS + (size_t)i * S;
  const int t = threadIdx.x;
  const int lane = t & 63, wave = t >> 6;
  __shared__ float red[4];

  float4 v[2];
  #pragma unroll
  for (int u = 0; u < 2; ++u) {
    const int base = (t + u * 256) * 4;
    if (base + 3 <= i) {
      v[u] = *(const float4*)(s + base);
    } else if (base > i) {
      v[u] = make_float4(-INFINITY, -INFINITY, -INFINITY, -INFINITY);
    } else {
      v[u].x = (base + 0 <= i) ? s[base + 0] : -INFINITY;
      v[u].y = (base + 1 <= i) ? s[base + 1] : -INFINITY;
      v[u].z = (base + 2 <= i) ? s[base + 2] : -INFINITY;
      v[u].w = (base + 3 <= i) ? s[base + 3] : -INFINITY;
    }
  }

  float m = -INFINITY;
  #pragma unroll
  for (int u = 0; u < 2; ++u)
    m = fmaxf(m, fmaxf(fmaxf(v[u].x, v[u].y), fmaxf(v[u].z, v[u].w)));
  m = wave_max(m);
  if (lane == 0) red[wave] = m;
  __syncthreads();
  m = fmaxf(fmaxf(red[0], red[1]), fmaxf(red[2], red[3]));
  __syncthreads();

  float sum = 0.f;
  #pragma unroll
  for (int u = 0; u < 2; ++u) {
    v[u].x = expf(v[u].x - m); sum += v[u].x;
    v[u].y = expf(v[u].y - m); sum += v[u].y;
    v[u].z = expf(v[u].z - m); sum += v[u].z;
    v[u].w = expf(v[u].w - m); sum += v[u].w;
  }
  sum = wave_sum(sum);
  if (lane == 0) red[wave] = sum;
  __syncthreads();
  sum = red[0] + red[1] + red[2] + red[3];
  const float inv = 1.f / sum;           // sum >= 1 (diag term is exp(0))

  const int dt_end = ((i >> 7) + 1) * 128;   // end of diagonal 128-tile
  #pragma unroll
  for (int u = 0; u < 2; ++u) {
    const int base = (t + u * 256) * 4;
    float4 w;
    w.x = v[u].x * inv; w.y = v[u].y * inv;
    w.z = v[u].z * inv; w.w = v[u].w * inv;
    *(float4*)(s + base) = w;            // f32 attn weights (0 above diag)
    if (base < dt_end) {
      ushort4 pk;
      pk.x = f2b(w.x); pk.y = f2b(w.y); pk.z = f2b(w.z); pk.w = f2b(w.w);
      *(ushort4*)((unsigned short*)p + base) = pk;
    }
  }
}

// ---- Stage D: O = P Vt^T (causal K-truncation), legacy 128x128 core ------
__global__ __launch_bounds__(256, 4)
void out_kernel(const bf16* __restrict__ P, const bf16* __restrict__ Vt,
                float* __restrict__ O)
{
  const int L = blockIdx.x;               // 0..511
  const int x = L & 7;                    // XCD
  const int s = L >> 3;                   // 0..63
  const int dt  = s & 7;
  const int qtb = ((s >> 3) << 3) | x;    // 0..63, fixed XCD per (b,qt)
  const int qt  = 15 - (qtb >> 2);        // heavy-first (large qt at low L)
  const int b   = qtb & 3;

  __shared__ __align__(16) bf16 As[BM * BK];
  __shared__ __align__(16) bf16 Bs[BN * BK];

  f32x4 acc[4][4];
  zero_acc(acc);
  const int ksteps = (qt + 1) * (128 / BK);   // only k <= q-block end nonzero
  gemm_core<false>(P + (size_t)b * SS_ELEMS + (size_t)qt * 128 * S,
                   Vt + (size_t)b * D * S + (size_t)dt * 128 * S,
                   S, S, ksteps, As, Bs, acc);

  const int lane = threadIdx.x & 63, wave = threadIdx.x >> 6;
  const int wm = (wave & 1) * 64, wn = (wave >> 1) * 64;
  const int col0 = lane & 15, row0 = (lane >> 4) * 4;
  #pragma unroll
  for (int mi = 0; mi < 4; ++mi)
    #pragma unroll
    for (int ni = 0; ni < 4; ++ni)
      #pragma unroll
      for (int r = 0; r < 4; ++r) {
        const int gq = qt * 128 + wm + mi * 16 + row0 + r;
        const int gd = dt * 128 + wn + ni * 16 + col0;
        O[((size_t)b * S + gq) * D + gd] = acc[mi][ni][r];
      }
}

extern "C" void kernel_launch(void* const* d_in, const int* in_sizes, int n_in,
                              void* d_out, int out_size, void* d_ws, size_t ws_size,
                              hipStream_t stream) {
  const float* X  = (const float*)d_in[0];
  // d_in[1] = causal mask (int32 tril) — applied analytically, not read.
  const float* Wq = (const float*)d_in[2];
  const float* Wk = (const float*)d_in[3];
  const float* Wv = (const float*)d_in[4];

  float* Out  = (float*)d_out;               // (4,2048,1024) f32
  float* Attn = Out + QK_ELEMS;              // (4,2048,2048) f32

  bf16* Q   = (bf16*)d_ws;                   // 16MB
  bf16* K   = Q + QK_ELEMS;                  // 16MB
  bf16* Vt  = K + QK_ELEMS;                  // 16MB
  bf16* Xb  = Vt + QK_ELEMS;                 // 16MB
  bf16* Wqb = Xb + QK_ELEMS;                 // 2MB
  bf16* Wkb = Wqb + W_ELEMS;                 // 2MB
  bf16* Wvb = Wkb + W_ELEMS;                 // 2MB  -> ws total 70MB
  bf16* Pb  = (bf16*)d_ws;                   // 32MB, aliases Q+K (dead by then)

  const int cvt_blocks = (int)((QK_ELEMS + 3 * W_ELEMS) / 4 / 256);
  cvt_kernel<<<cvt_blocks, 256, 0, stream>>>(X, Wq, Wk, Wv, Xb, Wqb, Wkb, Wvb);
  qkv_kernel<<<dim3(384), 512, 0, stream>>>(Xb, Wqb, Wkb, Wvb, Q, K, Vt);
  const int ntile = (S / 256) * (S / 256 + 1) / 2;   // 36
  scores_kernel<<<dim3(ntile, Bb), 512, 0, stream>>>(Q, K, Attn);
  softmax_kernel<<<dim3(Bb * S), 256, 0, stream>>>(Attn, Pb);
  out_kernel<<<dim3(512), 256, 0, stream>>>(Pb, Vt, Out);
}

// Round 7
// 281.582 us; speedup vs baseline: 1.1582x; 1.1582x over previous
//
#include <hip/hip_runtime.h>
#include <hip/hip_bf16.h>
#include <stdint.h>
#include <math.h>

// B=4, S=2048, D=1024 causal self-attention, f32 I/O.
// out = [output (4,2048,1024) | attn_weights (4,2048,2048)] flat f32.
// Pipeline: cvt(f32->bf16) -> fused QKV GEMM (Q,K row-major; V transposed)
// -> causal-tile scores GEMM (f32 into d_out attn region) -> in-place row
// softmax (+bf16 P copy) -> P.Vt GEMM (causal K-truncation, heavy-first).
// R12: FULL REVERT to R7 (verified 275.3us) + softmax expf -> __expf.
// R14: third submit of R12. Rounds 5+6 both died with the "container
// failed twice" infra signature; the same signature hit the VERIFIED R7
// source in round 0 and R9 in round 2, each clearing on resubmit, and
// round-4 timing showed acquire_s=111s (broker instability). Source is
// R7 + one VALU-shortening intrinsic swap — no hang mechanism exists.

typedef __hip_bfloat16 bf16;
typedef __attribute__((ext_vector_type(8))) short short8;
typedef __attribute__((ext_vector_type(4))) float f32x4;

#define BM 128
#define BN 128
#define BK 64

static constexpr int Bb = 4;
static constexpr int S  = 2048;
static constexpr int D  = 1024;
static constexpr size_t QK_ELEMS = (size_t)Bb * S * D;   // 8388608
static constexpr size_t SS_ELEMS = (size_t)S * S;        // 4194304 per batch
static constexpr size_t W_ELEMS  = (size_t)D * D;        // 1048576

__device__ __forceinline__ void async16(const bf16* g, bf16* l) {
  __builtin_amdgcn_global_load_lds(
      (__attribute__((address_space(1))) const void*)g,
      (__attribute__((address_space(3))) void*)l, 16, 0, 0);
}

// C[m,n] += sum_k A[m,k]*B[n,k]  (NT GEMM), 128x128 tile, BK=64, 4 waves,
// 16x16x32 bf16 MFMA. SWAP=true computes the transposed tile.
// LDS: row r x 8 chunks of 16B; slot s holds global K-chunk (s ^ (r&7)) ->
// conflict-free fragment reads (verified: SQ_LDS_BANK_CONFLICT 1.9e7 -> 0).
template<bool SWAP>
__device__ __forceinline__ void gemm_core(const bf16* __restrict__ A,
                                          const bf16* __restrict__ B,
                                          int ldA, int ldB, int ksteps,
                                          bf16* As, bf16* Bs,
                                          f32x4 acc[4][4])
{
  const int tid  = threadIdx.x;
  const int lane = tid & 63;
  const int wave = tid >> 6;
  const int wm   = (wave & 1) * 64;
  const int wn   = (wave >> 1) * 64;
  const int m16  = lane & 15;
  const int kq   = lane >> 4;
  const int sw   = m16 & 7;          // row-dependent swizzle key

  int r[4], f[4];
  #pragma unroll
  for (int i = 0; i < 4; ++i) {
    const int c = tid + i * 256;
    r[i] = c >> 3;
    f[i] = (((c & 7) ^ (r[i] & 7))) * 8;
  }

  for (int ks = 0; ks < ksteps; ++ks) {
    const int k = ks * BK;
    #pragma unroll
    for (int i = 0; i < 4; ++i)
      async16(A + (size_t)r[i] * ldA + k + f[i], As + ((size_t)tid + i * 256) * 8);
    #pragma unroll
    for (int i = 0; i < 4; ++i)
      async16(B + (size_t)r[i] * ldB + k + f[i], Bs + ((size_t)tid + i * 256) * 8);
    __syncthreads();

    #pragma unroll
    for (int j = 0; j < 2; ++j) {
      const int jc = j * 4 + kq;       // logical K-chunk for this lane
      const int sl = jc ^ sw;          // swizzled LDS slot within row
      short8 af[4], bfr[4];
      #pragma unroll
      for (int i = 0; i < 4; ++i)
        af[i] = *(const short8*)&As[((wm + i * 16 + m16) * 8 + sl) * 8];
      #pragma unroll
      for (int i = 0; i < 4; ++i)
        bfr[i] = *(const short8*)&Bs[((wn + i * 16 + m16) * 8 + sl) * 8];

      #pragma unroll
      for (int mi = 0; mi < 4; ++mi) {
        #pragma unroll
        for (int ni = 0; ni < 4; ++ni) {
          if (SWAP)
            acc[mi][ni] = __builtin_amdgcn_mfma_f32_16x16x32_bf16(
                bfr[ni], af[mi], acc[mi][ni], 0, 0, 0);
          else
            acc[mi][ni] = __builtin_amdgcn_mfma_f32_16x16x32_bf16(
                af[mi], bfr[ni], acc[mi][ni], 0, 0, 0);
        }
      }
    }
    __syncthreads();
  }
}

__device__ __forceinline__ void zero_acc(f32x4 acc[4][4]) {
  #pragma unroll
  for (int mi = 0; mi < 4; ++mi)
    #pragma unroll
    for (int ni = 0; ni < 4; ++ni)
      acc[mi][ni] = (f32x4){0.f, 0.f, 0.f, 0.f};
}

// ---- Stage 0: f32 -> bf16 conversion of X, Wq, Wk, Wv --------------------
__device__ __forceinline__ unsigned short f2b(float f) {
  __hip_bfloat16 h = __float2bfloat16(f);
  return *(unsigned short*)&h;
}

__global__ __launch_bounds__(256)
void cvt_kernel(const float* __restrict__ X,  const float* __restrict__ Wq,
                const float* __restrict__ Wk, const float* __restrict__ Wv,
                bf16* __restrict__ Xb, bf16* __restrict__ Wqb,
                bf16* __restrict__ Wkb, bf16* __restrict__ Wvb)
{
  const size_t g = ((size_t)blockIdx.x * 256 + threadIdx.x) * 4;
  const float* src; bf16* dst; size_t off;
  if (g < QK_ELEMS) { src = X; dst = Xb; off = g; }
  else {
    const size_t h = g - QK_ELEMS;
    const int w = (int)(h >> 20);
    off = h & (W_ELEMS - 1);
    src = (w == 0) ? Wq : (w == 1) ? Wk : Wv;
    dst = (w == 0) ? Wqb : (w == 1) ? Wkb : Wvb;
  }
  const float4 v = *(const float4*)(src + off);
  uint2 o;
  o.x = (uint32_t)f2b(v.x) | ((uint32_t)f2b(v.y) << 16);
  o.y = (uint32_t)f2b(v.z) | ((uint32_t)f2b(v.w) << 16);
  *(uint2*)((unsigned short*)dst + off) = o;
}

// ---- Stage A: fused QKV. z=0: Q, z=1: K (row-major); z=2: Vt (transposed)
// Linear grid 1536, XCD-aware decode: all nt (and all z) for one mt share
// one XCD -> each X row-tile fetched from HBM once (FETCH 178->44MB).
__global__ __launch_bounds__(256, 4)
void qkv_kernel(const bf16* __restrict__ X, const bf16* __restrict__ Wq,
                const bf16* __restrict__ Wk, const bf16* __restrict__ Wv,
                bf16* __restrict__ Q, bf16* __restrict__ Ko,
                bf16* __restrict__ Vt)
{
  __shared__ __align__(16) bf16 As[BM * BK];
  __shared__ __align__(16) bf16 Bs[BN * BK];
  const int L = blockIdx.x;               // 0..1535
  const int x = L & 7;                    // XCD (dispatch round-robin %8)
  const int s = L >> 3;                   // 0..191
  const int nt  = s & 7;
  const int zmt = ((s >> 3) << 3) | x;    // 0..191, fixed XCD per (z,mt)
  const int z   = zmt >> 6;
  const int mt  = zmt & 63;
  const bf16* W = (z == 0) ? Wq : (z == 1) ? Wk : Wv;

  const int lane = threadIdx.x & 63, wave = threadIdx.x >> 6;
  const int wm = (wave & 1) * 64, wn = (wave >> 1) * 64;
  const int col0 = lane & 15, row0 = (lane >> 4) * 4;

  f32x4 acc[4][4];
  zero_acc(acc);
  if (z < 2) {
    gemm_core<false>(X + (size_t)mt * 128 * D, W + (size_t)nt * 128 * D,
                     D, D, D / BK, As, Bs, acc);
    bf16* Out = z ? Ko : Q;
    #pragma unroll
    for (int mi = 0; mi < 4; ++mi)
      #pragma unroll
      for (int ni = 0; ni < 4; ++ni)
        #pragma unroll
        for (int r = 0; r < 4; ++r) {
          const int grow = mt * 128 + wm + mi * 16 + row0 + r;
          const int gcol = nt * 128 + wn + ni * 16 + col0;
          Out[(size_t)grow * D + gcol] = __float2bfloat16(acc[mi][ni][r]);
        }
  } else {
    gemm_core<true>(X + (size_t)mt * 128 * D, W + (size_t)nt * 128 * D,
                    D, D, D / BK, As, Bs, acc);
    const int b = (mt * 128) >> 11;
    #pragma unroll
    for (int mi = 0; mi < 4; ++mi)
      #pragma unroll
      for (int ni = 0; ni < 4; ++ni)
        #pragma unroll
        for (int r = 0; r < 4; ++r) {
          const int ge = nt * 128 + wn + ni * 16 + row0 + r;      // d index
          const int gs = mt * 128 + wm + mi * 16 + col0;          // s global
          const int sl = gs & (S - 1);
          Vt[(size_t)b * D * S + (size_t)ge * S + sl] = __float2bfloat16(acc[mi][ni][r]);
        }
  }
}

// ---- Stage B: Sc = Q K^T / 32 -> f32 into d_out attn region --------------
// Flattened lower-triangle tile grid: 136 tiles/batch, zero dead blocks.
__global__ __launch_bounds__(256, 4)
void scores_kernel(const bf16* __restrict__ Q, const bf16* __restrict__ K,
                   float* __restrict__ Sc)
{
  const int t = blockIdx.x, b = blockIdx.y;
  int qt = (int)((sqrtf(8.f * (float)t + 1.f) - 1.f) * 0.5f);
  while ((qt + 1) * (qt + 2) / 2 <= t) ++qt;
  while (qt * (qt + 1) / 2 > t) --qt;
  const int kt = t - qt * (qt + 1) / 2;

  __shared__ __align__(16) bf16 As[BM * BK];
  __shared__ __align__(16) bf16 Bs[BN * BK];

  f32x4 acc[4][4];
  zero_acc(acc);
  gemm_core<false>(Q + ((size_t)b * S + qt * 128) * D,
                   K + ((size_t)b * S + kt * 128) * D,
                   D, D, D / BK, As, Bs, acc);

  const int lane = threadIdx.x & 63, wave = threadIdx.x >> 6;
  const int wm = (wave & 1) * 64, wn = (wave >> 1) * 64;
  const int col0 = lane & 15, row0 = (lane >> 4) * 4;
  float* out = Sc + (size_t)b * SS_ELEMS;
  #pragma unroll
  for (int mi = 0; mi < 4; ++mi)
    #pragma unroll
    for (int ni = 0; ni < 4; ++ni)
      #pragma unroll
      for (int r = 0; r < 4; ++r) {
        const int gq = qt * 128 + wm + mi * 16 + row0 + r;
        const int gk = kt * 128 + wn + ni * 16 + col0;
        out[(size_t)gq * S + gk] = acc[mi][ni][r] * 0.03125f;
      }
}

// ---- Stage C: causal row softmax in place (f32) + bf16 P copy ------------
// float4 vectorized; skips loads above the diagonal; bf16 P written only up
// to the diagonal-tile end (out_kernel never reads past it).
__device__ __forceinline__ float wave_max(float v) {
  #pragma unroll
  for (int o = 32; o > 0; o >>= 1) v = fmaxf(v, __shfl_xor(v, o, 64));
  return v;
}
__device__ __forceinline__ float wave_sum(float v) {
  #pragma unroll
  for (int o = 32; o > 0; o >>= 1) v += __shfl_xor(v, o, 64);
  return v;
}

__global__ __launch_bounds__(256)
void softmax_kernel(float* __restrict__ Attn, bf16* __restrict__ Pb)
{
  const int row = blockIdx.x;            // 0..8191
  const int b = row >> 11, i = row & (S - 1);
  float* s = Attn + (size_t)b * SS_ELEMS + (size_t)i * S;
  bf16* p  = Pb   + (size_t)b * SS_ELEMS + (size_t)i * S;
  const int t = threadIdx.x;
  const int lane = t & 63, wave = t >> 6;
  __shared__ float red[4];

  float4 v[2];
  #pragma unroll
  for (int u = 0; u < 2; ++u) {
    const int base = (t + u * 256) * 4;
    if (base + 3 <= i) {
      v[u] = *(const float4*)(s + base);
    } else if (base > i) {
      v[u] = make_float4(-INFINITY, -INFINITY, -INFINITY, -INFINITY);
    } else {
      v[u].x = (base + 0 <= i) ? s[base + 0] : -INFINITY;
      v[u].y = (base + 1 <= i) ? s[base + 1] : -INFINITY;
      v[u].z = (base + 2 <= i) ? s[base + 2] : -INFINITY;
      v[u].w = (base + 3 <= i) ? s[base + 3] : -INFINITY;
    }
  }

  float m = -INFINITY;
  #pragma unroll
  for (int u = 0; u < 2; ++u)
    m = fmaxf(m, fmaxf(fmaxf(v[u].x, v[u].y), fmaxf(v[u].z, v[u].w)));
  m = wave_max(m);
  if (lane == 0) red[wave] = m;
  __syncthreads();
  m = fmaxf(fmaxf(red[0], red[1]), fmaxf(red[2], red[3]));
  __syncthreads();

  float sum = 0.f;
  #pragma unroll
  for (int u = 0; u < 2; ++u) {
    v[u].x = __expf(v[u].x - m); sum += v[u].x;
    v[u].y = __expf(v[u].y - m); sum += v[u].y;
    v[u].z = __expf(v[u].z - m); sum += v[u].z;
    v[u].w = __expf(v[u].w - m); sum += v[u].w;
  }
  sum = wave_sum(sum);
  if (lane == 0) red[wave] = sum;
  __syncthreads();
  sum = red[0] + red[1] + red[2] + red[3];
  const float inv = 1.f / sum;           // sum >= 1 (diag term is exp(0))

  const int dt_end = ((i >> 7) + 1) * 128;   // end of diagonal 128-tile
  #pragma unroll
  for (int u = 0; u < 2; ++u) {
    const int base = (t + u * 256) * 4;
    float4 w;
    w.x = v[u].x * inv; w.y = v[u].y * inv;
    w.z = v[u].z * inv; w.w = v[u].w * inv;
    *(float4*)(s + base) = w;            // f32 attn weights (0 above diag)
    if (base < dt_end) {
      ushort4 pk;
      pk.x = f2b(w.x); pk.y = f2b(w.y); pk.z = f2b(w.z); pk.w = f2b(w.w);
      *(ushort4*)((unsigned short*)p + base) = pk;
    }
  }
}

// ---- Stage D: O = P Vt^T (causal K-truncation) ---------------------------
// Linear grid 512, XCD-aware: all 8 dt of one (b,qt) share an XCD (P-strip
// L2 reuse); heavy-qt groups first.
__global__ __launch_bounds__(256, 4)
void out_kernel(const bf16* __restrict__ P, const bf16* __restrict__ Vt,
                float* __restrict__ O)
{
  const int L = blockIdx.x;               // 0..511
  const int x = L & 7;                    // XCD
  const int s = L >> 3;                   // 0..63
  const int dt  = s & 7;
  const int qtb = ((s >> 3) << 3) | x;    // 0..63, fixed XCD per (b,qt)
  const int qt  = 15 - (qtb >> 2);        // heavy-first (large qt at low L)
  const int b   = qtb & 3;

  __shared__ __align__(16) bf16 As[BM * BK];
  __shared__ __align__(16) bf16 Bs[BN * BK];

  f32x4 acc[4][4];
  zero_acc(acc);
  const int ksteps = (qt + 1) * (128 / BK);   // only k <= q-block end nonzero
  gemm_core<false>(P + (size_t)b * SS_ELEMS + (size_t)qt * 128 * S,
                   Vt + (size_t)b * D * S + (size_t)dt * 128 * S,
                   S, S, ksteps, As, Bs, acc);

  const int lane = threadIdx.x & 63, wave = threadIdx.x >> 6;
  const int wm = (wave & 1) * 64, wn = (wave >> 1) * 64;
  const int col0 = lane & 15, row0 = (lane >> 4) * 4;
  #pragma unroll
  for (int mi = 0; mi < 4; ++mi)
    #pragma unroll
    for (int ni = 0; ni < 4; ++ni)
      #pragma unroll
      for (int r = 0; r < 4; ++r) {
        const int gq = qt * 128 + wm + mi * 16 + row0 + r;
        const int gd = dt * 128 + wn + ni * 16 + col0;
        O[((size_t)b * S + gq) * D + gd] = acc[mi][ni][r];
      }
}

extern "C" void kernel_launch(void* const* d_in, const int* in_sizes, int n_in,
                              void* d_out, int out_size, void* d_ws, size_t ws_size,
                              hipStream_t stream) {
  const float* X  = (const float*)d_in[0];
  // d_in[1] = causal mask (int32 tril) — applied analytically, not read.
  const float* Wq = (const float*)d_in[2];
  const float* Wk = (const float*)d_in[3];
  const float* Wv = (const float*)d_in[4];

  float* Out  = (float*)d_out;               // (4,2048,1024) f32
  float* Attn = Out + QK_ELEMS;              // (4,2048,2048) f32

  bf16* Q   = (bf16*)d_ws;                   // 16MB
  bf16* K   = Q + QK_ELEMS;                  // 16MB
  bf16* Vt  = K + QK_ELEMS;                  // 16MB
  bf16* Xb  = Vt + QK_ELEMS;                 // 16MB
  bf16* Wqb = Xb + QK_ELEMS;                 // 2MB
  bf16* Wkb = Wqb + W_ELEMS;                 // 2MB
  bf16* Wvb = Wkb + W_ELEMS;                 // 2MB  -> ws total 70MB
  bf16* Pb  = (bf16*)d_ws;                   // 32MB, aliases Q+K (dead by then)

  const int cvt_blocks = (int)((QK_ELEMS + 3 * W_ELEMS) / 4 / 256);
  cvt_kernel<<<cvt_blocks, 256, 0, stream>>>(X, Wq, Wk, Wv, Xb, Wqb, Wkb, Wvb);
  qkv_kernel<<<dim3(1536), 256, 0, stream>>>(Xb, Wqb, Wkb, Wvb, Q, K, Vt);
  const int ntile = (S / 128) * (S / 128 + 1) / 2;   // 136
  scores_kernel<<<dim3(ntile, Bb), 256, 0, stream>>>(Q, K, Attn);
  softmax_kernel<<<dim3(Bb * S), 256, 0, stream>>>(Attn, Pb);
  out_kernel<<<dim3(512), 256, 0, stream>>>(Pb, Vt, Out);
}

// Round 8
// 267.139 us; speedup vs baseline: 1.2208x; 1.0541x over previous
//
#include <hip/hip_runtime.h>
#include <hip/hip_bf16.h>
#include <stdint.h>
#include <math.h>

// B=4, S=2048, D=1024 causal self-attention, f32 I/O.
// out = [output (4,2048,1024) | attn_weights (4,2048,2048)] flat f32.
// Pipeline: cvt(f32->bf16) -> fused QKV GEMM (legacy 128x128 core)
// -> causal scores GEMM -> in-place row softmax (+bf16 P) -> P.Vt GEMM.
// R15: scores+out moved to a 64x128-tile variant (gemm_core64) of the SAME
// verified 2-barrier core (identical swizzle/async16/sync structure; only
// tile geometry changes). Rationale: qkv (1536 blocks, 6/CU queued) runs at
// ~890TF but scores(544)/out(512) at ~2 blocks/CU expose the barrier-drain
// stall with no TLP cover -> est. ~200-300TF each. 64-row tiles double the
// grids (scores 1088, out 1024 blocks -> ~4/CU) at 24KB LDS/block.
// Kept: softmax __expf (R12, neutral-verified), heavy-first + XCD grouping.

typedef __hip_bfloat16 bf16;
typedef __attribute__((ext_vector_type(8))) short short8;
typedef __attribute__((ext_vector_type(4))) float f32x4;

#define BM 128
#define BN 128
#define BK 64

static constexpr int Bb = 4;
static constexpr int S  = 2048;
static constexpr int D  = 1024;
static constexpr size_t QK_ELEMS = (size_t)Bb * S * D;   // 8388608
static constexpr size_t SS_ELEMS = (size_t)S * S;        // 4194304 per batch
static constexpr size_t W_ELEMS  = (size_t)D * D;        // 1048576

__device__ __forceinline__ void async16(const bf16* g, bf16* l) {
  __builtin_amdgcn_global_load_lds(
      (__attribute__((address_space(1))) const void*)g,
      (__attribute__((address_space(3))) void*)l, 16, 0, 0);
}

// ============== legacy 128x128 core (qkv) — UNCHANGED, verified ===========
template<bool SWAP>
__device__ __forceinline__ void gemm_core(const bf16* __restrict__ A,
                                          const bf16* __restrict__ B,
                                          int ldA, int ldB, int ksteps,
                                          bf16* As, bf16* Bs,
                                          f32x4 acc[4][4])
{
  const int tid  = threadIdx.x;
  const int lane = tid & 63;
  const int wave = tid >> 6;
  const int wm   = (wave & 1) * 64;
  const int wn   = (wave >> 1) * 64;
  const int m16  = lane & 15;
  const int kq   = lane >> 4;
  const int sw   = m16 & 7;          // row-dependent swizzle key

  int r[4], f[4];
  #pragma unroll
  for (int i = 0; i < 4; ++i) {
    const int c = tid + i * 256;
    r[i] = c >> 3;
    f[i] = (((c & 7) ^ (r[i] & 7))) * 8;
  }

  for (int ks = 0; ks < ksteps; ++ks) {
    const int k = ks * BK;
    #pragma unroll
    for (int i = 0; i < 4; ++i)
      async16(A + (size_t)r[i] * ldA + k + f[i], As + ((size_t)tid + i * 256) * 8);
    #pragma unroll
    for (int i = 0; i < 4; ++i)
      async16(B + (size_t)r[i] * ldB + k + f[i], Bs + ((size_t)tid + i * 256) * 8);
    __syncthreads();

    #pragma unroll
    for (int j = 0; j < 2; ++j) {
      const int jc = j * 4 + kq;       // logical K-chunk for this lane
      const int sl = jc ^ sw;          // swizzled LDS slot within row
      short8 af[4], bfr[4];
      #pragma unroll
      for (int i = 0; i < 4; ++i)
        af[i] = *(const short8*)&As[((wm + i * 16 + m16) * 8 + sl) * 8];
      #pragma unroll
      for (int i = 0; i < 4; ++i)
        bfr[i] = *(const short8*)&Bs[((wn + i * 16 + m16) * 8 + sl) * 8];

      #pragma unroll
      for (int mi = 0; mi < 4; ++mi) {
        #pragma unroll
        for (int ni = 0; ni < 4; ++ni) {
          if (SWAP)
            acc[mi][ni] = __builtin_amdgcn_mfma_f32_16x16x32_bf16(
                bfr[ni], af[mi], acc[mi][ni], 0, 0, 0);
          else
            acc[mi][ni] = __builtin_amdgcn_mfma_f32_16x16x32_bf16(
                af[mi], bfr[ni], acc[mi][ni], 0, 0, 0);
        }
      }
    }
    __syncthreads();
  }
}

__device__ __forceinline__ void zero_acc(f32x4 acc[4][4]) {
  #pragma unroll
  for (int mi = 0; mi < 4; ++mi)
    #pragma unroll
    for (int ni = 0; ni < 4; ++ni)
      acc[mi][ni] = (f32x4){0.f, 0.f, 0.f, 0.f};
}

// ============== 64x128 tile core (scores/out) — same structure ============
// M=64, N=128, BK=64, 4 waves (each 64 rows x 32 cols; acc 4x2).
// LDS: As 64x64 (8KB), Bs 128x64 (16KB). Same row-swizzled slot layout and
// the same stage->syncthreads->mfma->syncthreads skeleton as gemm_core.
__device__ __forceinline__ void gemm_core64(const bf16* __restrict__ A,
                                            const bf16* __restrict__ B,
                                            int ldA, int ldB, int ksteps,
                                            bf16* As, bf16* Bs,
                                            f32x4 acc[4][2])
{
  const int tid  = threadIdx.x;
  const int lane = tid & 63;
  const int wave = tid >> 6;       // 0..3
  const int wn   = wave * 32;      // N col block of 32
  const int m16  = lane & 15;
  const int kq   = lane >> 4;
  const int sw   = m16 & 7;

  int ra[2], fa[2], rb[4], fb[4];
  #pragma unroll
  for (int i = 0; i < 2; ++i) {
    const int c = tid + i * 256;   // 0..511 -> A rows 0..63
    ra[i] = c >> 3;
    fa[i] = ((c & 7) ^ (ra[i] & 7)) * 8;
  }
  #pragma unroll
  for (int i = 0; i < 4; ++i) {
    const int c = tid + i * 256;   // 0..1023 -> B rows 0..127
    rb[i] = c >> 3;
    fb[i] = ((c & 7) ^ (rb[i] & 7)) * 8;
  }

  for (int ks = 0; ks < ksteps; ++ks) {
    const int k = ks * BK;
    #pragma unroll
    for (int i = 0; i < 2; ++i)
      async16(A + (size_t)ra[i] * ldA + k + fa[i], As + ((size_t)tid + i * 256) * 8);
    #pragma unroll
    for (int i = 0; i < 4; ++i)
      async16(B + (size_t)rb[i] * ldB + k + fb[i], Bs + ((size_t)tid + i * 256) * 8);
    __syncthreads();

    #pragma unroll
    for (int j = 0; j < 2; ++j) {
      const int jc = j * 4 + kq;
      const int sl = jc ^ sw;
      short8 af[4], bfr[2];
      #pragma unroll
      for (int i = 0; i < 4; ++i)
        af[i] = *(const short8*)&As[((i * 16 + m16) * 8 + sl) * 8];
      #pragma unroll
      for (int i = 0; i < 2; ++i)
        bfr[i] = *(const short8*)&Bs[((wn + i * 16 + m16) * 8 + sl) * 8];

      #pragma unroll
      for (int mi = 0; mi < 4; ++mi)
        #pragma unroll
        for (int ni = 0; ni < 2; ++ni)
          acc[mi][ni] = __builtin_amdgcn_mfma_f32_16x16x32_bf16(
              af[mi], bfr[ni], acc[mi][ni], 0, 0, 0);
    }
    __syncthreads();
  }
}

__device__ __forceinline__ void zero_acc64(f32x4 acc[4][2]) {
  #pragma unroll
  for (int mi = 0; mi < 4; ++mi)
    #pragma unroll
    for (int ni = 0; ni < 2; ++ni)
      acc[mi][ni] = (f32x4){0.f, 0.f, 0.f, 0.f};
}

// ---- Stage 0: f32 -> bf16 conversion of X, Wq, Wk, Wv --------------------
__device__ __forceinline__ unsigned short f2b(float f) {
  __hip_bfloat16 h = __float2bfloat16(f);
  return *(unsigned short*)&h;
}

__global__ __launch_bounds__(256)
void cvt_kernel(const float* __restrict__ X,  const float* __restrict__ Wq,
                const float* __restrict__ Wk, const float* __restrict__ Wv,
                bf16* __restrict__ Xb, bf16* __restrict__ Wqb,
                bf16* __restrict__ Wkb, bf16* __restrict__ Wvb)
{
  const size_t g = ((size_t)blockIdx.x * 256 + threadIdx.x) * 4;
  const float* src; bf16* dst; size_t off;
  if (g < QK_ELEMS) { src = X; dst = Xb; off = g; }
  else {
    const size_t h = g - QK_ELEMS;
    const int w = (int)(h >> 20);
    off = h & (W_ELEMS - 1);
    src = (w == 0) ? Wq : (w == 1) ? Wk : Wv;
    dst = (w == 0) ? Wqb : (w == 1) ? Wkb : Wvb;
  }
  const float4 v = *(const float4*)(src + off);
  uint2 o;
  o.x = (uint32_t)f2b(v.x) | ((uint32_t)f2b(v.y) << 16);
  o.y = (uint32_t)f2b(v.z) | ((uint32_t)f2b(v.w) << 16);
  *(uint2*)((unsigned short*)dst + off) = o;
}

// ---- Stage A: fused QKV (legacy core, UNCHANGED) -------------------------
__global__ __launch_bounds__(256, 4)
void qkv_kernel(const bf16* __restrict__ X, const bf16* __restrict__ Wq,
                const bf16* __restrict__ Wk, const bf16* __restrict__ Wv,
                bf16* __restrict__ Q, bf16* __restrict__ Ko,
                bf16* __restrict__ Vt)
{
  __shared__ __align__(16) bf16 As[BM * BK];
  __shared__ __align__(16) bf16 Bs[BN * BK];
  const int L = blockIdx.x;               // 0..1535
  const int x = L & 7;                    // XCD (dispatch round-robin %8)
  const int s = L >> 3;                   // 0..191
  const int nt  = s & 7;
  const int zmt = ((s >> 3) << 3) | x;    // 0..191, fixed XCD per (z,mt)
  const int z   = zmt >> 6;
  const int mt  = zmt & 63;
  const bf16* W = (z == 0) ? Wq : (z == 1) ? Wk : Wv;

  const int lane = threadIdx.x & 63, wave = threadIdx.x >> 6;
  const int wm = (wave & 1) * 64, wn = (wave >> 1) * 64;
  const int col0 = lane & 15, row0 = (lane >> 4) * 4;

  f32x4 acc[4][4];
  zero_acc(acc);
  if (z < 2) {
    gemm_core<false>(X + (size_t)mt * 128 * D, W + (size_t)nt * 128 * D,
                     D, D, D / BK, As, Bs, acc);
    bf16* Out = z ? Ko : Q;
    #pragma unroll
    for (int mi = 0; mi < 4; ++mi)
      #pragma unroll
      for (int ni = 0; ni < 4; ++ni)
        #pragma unroll
        for (int r = 0; r < 4; ++r) {
          const int grow = mt * 128 + wm + mi * 16 + row0 + r;
          const int gcol = nt * 128 + wn + ni * 16 + col0;
          Out[(size_t)grow * D + gcol] = __float2bfloat16(acc[mi][ni][r]);
        }
  } else {
    gemm_core<true>(X + (size_t)mt * 128 * D, W + (size_t)nt * 128 * D,
                    D, D, D / BK, As, Bs, acc);
    const int b = (mt * 128) >> 11;
    #pragma unroll
    for (int mi = 0; mi < 4; ++mi)
      #pragma unroll
      for (int ni = 0; ni < 4; ++ni)
        #pragma unroll
        for (int r = 0; r < 4; ++r) {
          const int ge = nt * 128 + wn + ni * 16 + row0 + r;      // d index
          const int gs = mt * 128 + wm + mi * 16 + col0;          // s global
          const int sl = gs & (S - 1);
          Vt[(size_t)b * D * S + (size_t)ge * S + sl] = __float2bfloat16(acc[mi][ni][r]);
        }
  }
}

// ---- Stage B: Sc = Q K^T / 32, 64x128 tiles. 272 tiles/batch, 1088 blocks.
// Tile (qi,kt): rows [qi*64, qi*64+64), cols [kt*128, kt*128+128),
// kt in 0..(qi>>1). Pair decode: pair m starts at t = m*(m+1).
__global__ __launch_bounds__(256, 4)
void scores_kernel(const bf16* __restrict__ Q, const bf16* __restrict__ K,
                   float* __restrict__ Sc)
{
  const int t = blockIdx.x, b = blockIdx.y;
  int m = (int)((sqrtf(4.f * (float)t + 1.f) - 1.f) * 0.5f);
  while ((m + 1) * (m + 2) <= t) ++m;
  while (m * (m + 1) > t) --m;
  const int r_ = t - m * (m + 1);           // 0 .. 2m+1
  const int qi = 2 * m + (r_ > m ? 1 : 0);  // 64-row block 0..31
  const int kt = (r_ > m) ? (r_ - (m + 1)) : r_;

  __shared__ __align__(16) bf16 As[64 * BK];
  __shared__ __align__(16) bf16 Bs[128 * BK];

  f32x4 acc[4][2];
  zero_acc64(acc);
  gemm_core64(Q + ((size_t)b * S + qi * 64) * D,
              K + ((size_t)b * S + kt * 128) * D,
              D, D, D / BK, As, Bs, acc);

  const int lane = threadIdx.x & 63, wave = threadIdx.x >> 6;
  const int col0 = lane & 15, row0 = (lane >> 4) * 4;
  float* out = Sc + (size_t)b * SS_ELEMS;
  #pragma unroll
  for (int mi = 0; mi < 4; ++mi)
    #pragma unroll
    for (int ni = 0; ni < 2; ++ni)
      #pragma unroll
      for (int r = 0; r < 4; ++r) {
        const int gq = qi * 64 + mi * 16 + row0 + r;
        const int gk = kt * 128 + wave * 32 + ni * 16 + col0;
        out[(size_t)gq * S + gk] = acc[mi][ni][r] * 0.03125f;
      }
}

// ---- Stage C: causal row softmax in place (f32) + bf16 P copy ------------
__device__ __forceinline__ float wave_max(float v) {
  #pragma unroll
  for (int o = 32; o > 0; o >>= 1) v = fmaxf(v, __shfl_xor(v, o, 64));
  return v;
}
__device__ __forceinline__ float wave_sum(float v) {
  #pragma unroll
  for (int o = 32; o > 0; o >>= 1) v += __shfl_xor(v, o, 64);
  return v;
}

__global__ __launch_bounds__(256)
void softmax_kernel(float* __restrict__ Attn, bf16* __restrict__ Pb)
{
  const int row = blockIdx.x;            // 0..8191
  const int b = row >> 11, i = row & (S - 1);
  float* s = Attn + (size_t)b * SS_ELEMS + (size_t)i * S;
  bf16* p  = Pb   + (size_t)b * SS_ELEMS + (size_t)i * S;
  const int t = threadIdx.x;
  const int lane = t & 63, wave = t >> 6;
  __shared__ float red[4];

  float4 v[2];
  #pragma unroll
  for (int u = 0; u < 2; ++u) {
    const int base = (t + u * 256) * 4;
    if (base + 3 <= i) {
      v[u] = *(const float4*)(s + base);
    } else if (base > i) {
      v[u] = make_float4(-INFINITY, -INFINITY, -INFINITY, -INFINITY);
    } else {
      v[u].x = (base + 0 <= i) ? s[base + 0] : -INFINITY;
      v[u].y = (base + 1 <= i) ? s[base + 1] : -INFINITY;
      v[u].z = (base + 2 <= i) ? s[base + 2] : -INFINITY;
      v[u].w = (base + 3 <= i) ? s[base + 3] : -INFINITY;
    }
  }

  float m = -INFINITY;
  #pragma unroll
  for (int u = 0; u < 2; ++u)
    m = fmaxf(m, fmaxf(fmaxf(v[u].x, v[u].y), fmaxf(v[u].z, v[u].w)));
  m = wave_max(m);
  if (lane == 0) red[wave] = m;
  __syncthreads();
  m = fmaxf(fmaxf(red[0], red[1]), fmaxf(red[2], red[3]));
  __syncthreads();

  float sum = 0.f;
  #pragma unroll
  for (int u = 0; u < 2; ++u) {
    v[u].x = __expf(v[u].x - m); sum += v[u].x;
    v[u].y = __expf(v[u].y - m); sum += v[u].y;
    v[u].z = __expf(v[u].z - m); sum += v[u].z;
    v[u].w = __expf(v[u].w - m); sum += v[u].w;
  }
  sum = wave_sum(sum);
  if (lane == 0) red[wave] = sum;
  __syncthreads();
  sum = red[0] + red[1] + red[2] + red[3];
  const float inv = 1.f / sum;           // sum >= 1 (diag term is exp(0))

  const int dt_end = ((i >> 7) + 1) * 128;   // end of diagonal 128-tile
  #pragma unroll
  for (int u = 0; u < 2; ++u) {
    const int base = (t + u * 256) * 4;
    float4 w;
    w.x = v[u].x * inv; w.y = v[u].y * inv;
    w.z = v[u].z * inv; w.w = v[u].w * inv;
    *(float4*)(s + base) = w;            // f32 attn weights (0 above diag)
    if (base < dt_end) {
      ushort4 pk;
      pk.x = f2b(w.x); pk.y = f2b(w.y); pk.z = f2b(w.z); pk.w = f2b(w.w);
      *(ushort4*)((unsigned short*)p + base) = pk;
    }
  }
}

// ---- Stage D: O = P Vt^T, 64x128 tiles, causal K-truncation. -------------
// 1024 blocks. XCD decode: all 8 dt of one (b,Q) consecutive per XCD
// (P-strip L2 reuse); heavy-Q first. ksteps = Q+1 (BK=64; covers k <= row).
__global__ __launch_bounds__(256, 4)
void out_kernel(const bf16* __restrict__ P, const bf16* __restrict__ Vt,
                float* __restrict__ O)
{
  const int L = blockIdx.x;               // 0..1023
  const int x = L & 7;                    // XCD
  const int s = L >> 3;                   // 0..127
  const int dt  = s & 7;
  const int qb  = ((s >> 3) << 3) | x;    // 0..127, fixed XCD per (b,Q)
  const int Qi  = 31 - (qb >> 2);         // heavy-first 64-row block 0..31
  const int b   = qb & 3;

  __shared__ __align__(16) bf16 As[64 * BK];
  __shared__ __align__(16) bf16 Bs[128 * BK];

  f32x4 acc[4][2];
  zero_acc64(acc);
  gemm_core64(P + (size_t)b * SS_ELEMS + (size_t)Qi * 64 * S,
              Vt + (size_t)b * D * S + (size_t)dt * 128 * S,
              S, S, Qi + 1, As, Bs, acc);

  const int lane = threadIdx.x & 63, wave = threadIdx.x >> 6;
  const int col0 = lane & 15, row0 = (lane >> 4) * 4;
  #pragma unroll
  for (int mi = 0; mi < 4; ++mi)
    #pragma unroll
    for (int ni = 0; ni < 2; ++ni)
      #pragma unroll
      for (int r = 0; r < 4; ++r) {
        const int gq = Qi * 64 + mi * 16 + row0 + r;
        const int gd = dt * 128 + wave * 32 + ni * 16 + col0;
        O[((size_t)b * S + gq) * D + gd] = acc[mi][ni][r];
      }
}

extern "C" void kernel_launch(void* const* d_in, const int* in_sizes, int n_in,
                              void* d_out, int out_size, void* d_ws, size_t ws_size,
                              hipStream_t stream) {
  const float* X  = (const float*)d_in[0];
  // d_in[1] = causal mask (int32 tril) — applied analytically, not read.
  const float* Wq = (const float*)d_in[2];
  const float* Wk = (const float*)d_in[3];
  const float* Wv = (const float*)d_in[4];

  float* Out  = (float*)d_out;               // (4,2048,1024) f32
  float* Attn = Out + QK_ELEMS;              // (4,2048,2048) f32

  bf16* Q   = (bf16*)d_ws;                   // 16MB
  bf16* K   = Q + QK_ELEMS;                  // 16MB
  bf16* Vt  = K + QK_ELEMS;                  // 16MB
  bf16* Xb  = Vt + QK_ELEMS;                 // 16MB
  bf16* Wqb = Xb + QK_ELEMS;                 // 2MB
  bf16* Wkb = Wqb + W_ELEMS;                 // 2MB
  bf16* Wvb = Wkb + W_ELEMS;                 // 2MB  -> ws total 70MB
  bf16* Pb  = (bf16*)d_ws;                   // 32MB, aliases Q+K (dead by then)

  const int cvt_blocks = (int)((QK_ELEMS + 3 * W_ELEMS) / 4 / 256);
  cvt_kernel<<<cvt_blocks, 256, 0, stream>>>(X, Wq, Wk, Wv, Xb, Wqb, Wkb, Wvb);
  qkv_kernel<<<dim3(1536), 256, 0, stream>>>(Xb, Wqb, Wkb, Wvb, Q, K, Vt);
  const int ntile64 = 2 * (S / 128) * (S / 128 + 1) / 2;   // 272
  scores_kernel<<<dim3(ntile64, Bb), 256, 0, stream>>>(Q, K, Attn);
  softmax_kernel<<<dim3(Bb * S), 256, 0, stream>>>(Attn, Pb);
  out_kernel<<<dim3(1024), 256, 0, stream>>>(Pb, Vt, Out);
}